// Round 1
// baseline (2438.226 us; speedup 1.0000x reference)
//
#include <hip/hip_runtime.h>

#define NN 30000
#define NE 480000
#define NR 16
#define D  128
#define NT 200000
#define AST 132   // padded LDS row stride (floats) for row-major tiles

// ---------------- prep kernels ----------------

__global__ void k_gather_x(const float* __restrict__ node_emb,
                           const int* __restrict__ local_nodes,
                           float* __restrict__ x) {
  int i4 = blockIdx.x * blockDim.x + threadIdx.x;
  if (i4 >= NN * (D / 4)) return;
  int n = i4 >> 5, c = i4 & 31;
  int src = local_nodes[n];
  reinterpret_cast<float4*>(x)[i4] =
      reinterpret_cast<const float4*>(node_emb)[(size_t)src * 32 + c];
}

__global__ void k_hist(const int* __restrict__ etype, int* __restrict__ cnt) {
  __shared__ int h[NR];
  if (threadIdx.x < NR) h[threadIdx.x] = 0;
  __syncthreads();
  int e = blockIdx.x * blockDim.x + threadIdx.x;
  if (e < NE) atomicAdd(&h[etype[e]], 1);
  __syncthreads();
  if (threadIdx.x < NR) atomicAdd(&cnt[threadIdx.x], h[threadIdx.x]);
}

__global__ void k_scan(const int* __restrict__ cnt, int* __restrict__ off,
                       int* __restrict__ cur) {
  if (threadIdx.x == 0) {
    int o = 0;
    for (int r = 0; r < NR; ++r) { off[r] = o; cur[r] = o; o += cnt[r]; }
  }
}

__global__ void k_bucket(const int* __restrict__ ei, const int* __restrict__ etype,
                         int* __restrict__ cur, int* __restrict__ srcs,
                         int* __restrict__ dsts, float* __restrict__ deg) {
  __shared__ int h[NR], base[NR];
  if (threadIdx.x < NR) h[threadIdx.x] = 0;
  __syncthreads();
  int e = blockIdx.x * blockDim.x + threadIdx.x;
  int t = 0, loc = 0;
  bool act = (e < NE);
  if (act) { t = etype[e]; loc = atomicAdd(&h[t], 1); }
  __syncthreads();
  if (threadIdx.x < NR)
    base[threadIdx.x] = atomicAdd(&cur[threadIdx.x], h[threadIdx.x]);
  __syncthreads();
  if (act) {
    int p = base[t] + loc;
    int d = ei[NE + e];
    srcs[p] = ei[e];
    dsts[p] = d;
    atomicAdd(&deg[d], 1.0f);
  }
}

// ---------------- self-loop GEMM: y = x @ Ww^T + b ----------------
// Ww is [out][in] (torch Linear layout) -> both operands k-major: dot-product form.

__launch_bounds__(256, 1)
__global__ void k_self_gemm(const float* __restrict__ x, const float* __restrict__ Ww,
                            const float* __restrict__ Wb, float* __restrict__ y) {
  __shared__ float Xl[D][AST];
  __shared__ float Wl[D][AST];   // [o][k], natural copy, padded stride
  const int n0 = blockIdx.x * D;

  for (int i4 = threadIdx.x; i4 < D * D / 4; i4 += 256) {
    int o = i4 >> 5, kc = i4 & 31;
    *reinterpret_cast<float4*>(&Wl[o][4 * kc]) =
        reinterpret_cast<const float4*>(Ww)[i4];
  }
  for (int i4 = threadIdx.x; i4 < D * D / 4; i4 += 256) {
    int n = i4 >> 5, kc = i4 & 31;
    float4 v = make_float4(0.f, 0.f, 0.f, 0.f);
    if (n0 + n < NN)
      v = reinterpret_cast<const float4*>(x)[(size_t)(n0 + n) * 32 + kc];
    *reinterpret_cast<float4*>(&Xl[n][4 * kc]) = v;
  }
  __syncthreads();

  const int tx = threadIdx.x & 15, ty = threadIdx.x >> 4;
  float acc[8][8];
#pragma unroll
  for (int j = 0; j < 8; ++j)
#pragma unroll
    for (int m = 0; m < 8; ++m) acc[j][m] = 0.f;

  for (int k = 0; k < D; k += 4) {
    float4 a[8], w[8];
#pragma unroll
    for (int j = 0; j < 8; ++j)
      a[j] = *reinterpret_cast<const float4*>(&Xl[ty + 16 * j][k]);
#pragma unroll
    for (int m = 0; m < 8; ++m)
      w[m] = *reinterpret_cast<const float4*>(&Wl[tx + 16 * m][k]);
#pragma unroll
    for (int j = 0; j < 8; ++j)
#pragma unroll
      for (int m = 0; m < 8; ++m)
        acc[j][m] += a[j].x * w[m].x + a[j].y * w[m].y +
                     a[j].z * w[m].z + a[j].w * w[m].w;
  }

#pragma unroll
  for (int m = 0; m < 8; ++m) {
    int o = tx + 16 * m;
    float b = Wb[o];
#pragma unroll
    for (int j = 0; j < 8; ++j) {
      int gn = n0 + ty + 16 * j;
      if (gn < NN) y[(size_t)gn * D + o] = acc[j][m] + b;
    }
  }
}

// ---------------- per-relation message GEMM ----------------
// For relation r: msg[e][o] = sum_k x[src_e][k] * W_r[k][o]; atomicAdd into agg[dst_e].

__launch_bounds__(256, 1)
__global__ void k_msg_gemm(const float* __restrict__ x, const float* __restrict__ Wrel,
                           const int* __restrict__ srcs, const int* __restrict__ dsts,
                           const int* __restrict__ roff, const int* __restrict__ rcnt,
                           float* __restrict__ agg) {
  __shared__ float Al[D][AST];
  __shared__ float Wl[D][D];   // [k][o], natural layout (conflict-free copy & reads)
  const int r = blockIdx.y;
  const int cnt = rcnt[r];
  const int base0 = roff[r];
  const float* __restrict__ Wr = Wrel + (size_t)r * D * D;

  for (int i4 = threadIdx.x; i4 < D * D / 4; i4 += 256)
    reinterpret_cast<float4*>(Wl)[i4] = reinterpret_cast<const float4*>(Wr)[i4];

  const int wave = threadIdx.x >> 6, lane = threadIdx.x & 63;
  const int tx = threadIdx.x & 15, ty = threadIdx.x >> 4;

  for (int t0 = blockIdx.x * D; t0 < cnt; t0 += gridDim.x * D) {
    const int nE = min(D, cnt - t0);
    // gather up to 128 x-rows into LDS (one wave per row, float2/lane, coalesced)
#pragma unroll 4
    for (int e = wave; e < D; e += 4) {
      float2 v = make_float2(0.f, 0.f);
      if (e < nE) {
        int srow = srcs[base0 + t0 + e];
        v = reinterpret_cast<const float2*>(x + (size_t)srow * D)[lane];
      }
      *reinterpret_cast<float2*>(&Al[e][2 * lane]) = v;
    }
    __syncthreads();

    float acc[8][8];
#pragma unroll
    for (int j = 0; j < 8; ++j)
#pragma unroll
      for (int m = 0; m < 8; ++m) acc[j][m] = 0.f;

    for (int k = 0; k < D; k += 4) {
      float4 a[8];
#pragma unroll
      for (int j = 0; j < 8; ++j)
        a[j] = *reinterpret_cast<const float4*>(&Al[ty + 16 * j][k]);
#pragma unroll
      for (int kk = 0; kk < 4; ++kk) {
        float4 w0 = *reinterpret_cast<const float4*>(&Wl[k + kk][4 * tx]);
        float4 w1 = *reinterpret_cast<const float4*>(&Wl[k + kk][4 * tx + 64]);
#pragma unroll
        for (int j = 0; j < 8; ++j) {
          float av = (kk == 0) ? a[j].x : (kk == 1) ? a[j].y
                   : (kk == 2) ? a[j].z : a[j].w;
          acc[j][0] += av * w0.x; acc[j][1] += av * w0.y;
          acc[j][2] += av * w0.z; acc[j][3] += av * w0.w;
          acc[j][4] += av * w1.x; acc[j][5] += av * w1.y;
          acc[j][6] += av * w1.z; acc[j][7] += av * w1.w;
        }
      }
    }
    __syncthreads();   // all LDS reads done before next tile's gather

#pragma unroll
    for (int j = 0; j < 8; ++j) {
      int e = ty + 16 * j;
      if (e < nE) {
        float* arow = agg + (size_t)dsts[base0 + t0 + e] * D;
#pragma unroll
        for (int c = 0; c < 4; ++c) {
          atomicAdd(arow + 4 * tx + c,      acc[j][c]);
          atomicAdd(arow + 4 * tx + 64 + c, acc[j][4 + c]);
        }
      }
    }
  }
}

// ---------------- combine: x = relu(y + agg/deg); re-zero agg ----------------

__global__ void k_combine(float* __restrict__ y, float* __restrict__ agg,
                          const float* __restrict__ deg) {
  int i4 = blockIdx.x * blockDim.x + threadIdx.x;
  if (i4 >= NN * 32) return;
  float d = deg[i4 >> 5];
  float inv = 1.0f / fmaxf(d, 1.0f);
  float4 a = reinterpret_cast<float4*>(agg)[i4];
  float4 v = reinterpret_cast<float4*>(y)[i4];
  v.x = fmaxf(fmaf(a.x, inv, v.x), 0.f);
  v.y = fmaxf(fmaf(a.y, inv, v.y), 0.f);
  v.z = fmaxf(fmaf(a.z, inv, v.z), 0.f);
  v.w = fmaxf(fmaf(a.w, inv, v.w), 0.f);
  reinterpret_cast<float4*>(y)[i4] = v;
  reinterpret_cast<float4*>(agg)[i4] = make_float4(0.f, 0.f, 0.f, 0.f);
}

// ---------------- DistMult scoring ----------------

__global__ void k_score(const float* __restrict__ x, const float* __restrict__ rel,
                        const int* __restrict__ hh, const int* __restrict__ rr,
                        const int* __restrict__ tt, float* __restrict__ out) {
  int gw = (blockIdx.x * blockDim.x + threadIdx.x) >> 6;
  int lane = threadIdx.x & 63;
  int nw = (gridDim.x * blockDim.x) >> 6;
  for (int i = gw; i < NT; i += nw) {
    const float2* ph = reinterpret_cast<const float2*>(x + (size_t)hh[i] * D);
    const float2* pr = reinterpret_cast<const float2*>(rel + (size_t)rr[i] * D);
    const float2* pt = reinterpret_cast<const float2*>(x + (size_t)tt[i] * D);
    float2 a = ph[lane], b = pr[lane], c = pt[lane];
    float v = a.x * b.x * c.x + a.y * b.y * c.y;
#pragma unroll
    for (int m = 32; m; m >>= 1) v += __shfl_xor(v, m);
    if (lane == 0) out[i] = v;
  }
}

// ---------------- launch ----------------

extern "C" void kernel_launch(void* const* d_in, const int* in_sizes, int n_in,
                              void* d_out, int out_size, void* d_ws, size_t ws_size,
                              hipStream_t stream) {
  const float* node_emb = (const float*)d_in[0];
  const float* rel_emb  = (const float*)d_in[1];
  const float* W_rel0   = (const float*)d_in[2];
  const float* Wself_w0 = (const float*)d_in[3];
  const float* Wself_b0 = (const float*)d_in[4];
  const float* W_rel1   = (const float*)d_in[5];
  const float* Wself_w1 = (const float*)d_in[6];
  const float* Wself_b1 = (const float*)d_in[7];
  const int* local_nodes = (const int*)d_in[8];
  const int* edge_index  = (const int*)d_in[9];
  const int* edge_type   = (const int*)d_in[10];
  const int* h_loc = (const int*)d_in[11];
  const int* r_ids = (const int*)d_in[12];
  const int* t_loc = (const int*)d_in[13];
  float* out = (float*)d_out;

  // workspace layout (bytes)
  char* ws = (char*)d_ws;
  float* x_a  = (float*)(ws + 0);          // 15,360,000
  float* x_b  = (float*)(ws + 15360000);   // 15,360,000
  float* agg  = (float*)(ws + 30720000);   // 15,360,000
  float* deg  = (float*)(ws + 46080000);   //    120,000
  int* rel_cnt = (int*)(ws + 46200000);    //         64
  int* rel_off = (int*)(ws + 46200064);
  int* rel_cur = (int*)(ws + 46200128);
  int* srcs    = (int*)(ws + 46200192);    //  1,920,000
  int* dsts    = (int*)(ws + 48120192);    //  1,920,000
  if (ws_size < (size_t)50040192) return;  // insufficient scratch (constant behavior)

  // zero agg + deg + rel_cnt in one contiguous memset
  hipMemsetAsync(ws + 30720000, 0, 15480064, stream);

  k_gather_x<<<3750, 256, 0, stream>>>(node_emb, local_nodes, x_a);
  k_hist<<<1875, 256, 0, stream>>>(edge_type, rel_cnt);
  k_scan<<<1, 64, 0, stream>>>(rel_cnt, rel_off, rel_cur);
  k_bucket<<<1875, 256, 0, stream>>>(edge_index, edge_type, rel_cur, srcs, dsts, deg);

  // layer 0
  k_self_gemm<<<235, 256, 0, stream>>>(x_a, Wself_w0, Wself_b0, x_b);
  k_msg_gemm<<<dim3(256, 16), 256, 0, stream>>>(x_a, W_rel0, srcs, dsts,
                                                rel_off, rel_cnt, agg);
  k_combine<<<3750, 256, 0, stream>>>(x_b, agg, deg);

  // layer 1
  k_self_gemm<<<235, 256, 0, stream>>>(x_b, Wself_w1, Wself_b1, x_a);
  k_msg_gemm<<<dim3(256, 16), 256, 0, stream>>>(x_b, W_rel1, srcs, dsts,
                                                rel_off, rel_cnt, agg);
  k_combine<<<3750, 256, 0, stream>>>(x_a, agg, deg);

  k_score<<<1024, 256, 0, stream>>>(x_a, rel_emb, h_loc, r_ids, t_loc, out);
}

// Round 2
// 1430.907 us; speedup vs baseline: 1.7040x; 1.7040x over previous
//
#include <hip/hip_runtime.h>

#define NN 30000
#define NE 480000
#define NR 16
#define D  128
#define NT 200000
#define AST 132                 // padded LDS row stride (floats); rows stay 16B-aligned
#define NBLK 235                // ceil(NN/128)
#define NBINS (NBLK * NR)       // 3760

// ---------------- prep kernels ----------------

__global__ void k_gather_x(const float* __restrict__ node_emb,
                           const int* __restrict__ local_nodes,
                           float* __restrict__ x) {
  int i4 = blockIdx.x * blockDim.x + threadIdx.x;
  if (i4 >= NN * (D / 4)) return;
  int n = i4 >> 5, c = i4 & 31;
  int src = local_nodes[n];
  reinterpret_cast<float4*>(x)[i4] =
      reinterpret_cast<const float4*>(node_emb)[(size_t)src * 32 + c];
}

__global__ void k_hist_bins(const int* __restrict__ ei, const int* __restrict__ et,
                            int* __restrict__ bins) {
  int e = blockIdx.x * blockDim.x + threadIdx.x;
  if (e >= NE) return;
  int d = ei[NE + e], r = et[e];
  atomicAdd(&bins[(d >> 7) * NR + r], 1);
}

__global__ void k_scan_bins(const int* __restrict__ bins, int* __restrict__ off,
                            int* __restrict__ cur) {
  __shared__ int ps[1024];
  const int t = threadIdx.x;
  const int base = t * 4;
  int c[4], s0 = 0;
#pragma unroll
  for (int u = 0; u < 4; ++u) {
    int b = base + u;
    c[u] = (b < NBINS) ? bins[b] : 0;
    s0 += c[u];
  }
  ps[t] = s0;
  __syncthreads();
  for (int dstep = 1; dstep < 1024; dstep <<= 1) {
    int v = (t >= dstep) ? ps[t - dstep] : 0;
    __syncthreads();
    ps[t] += v;
    __syncthreads();
  }
  int ex = ps[t] - s0;   // exclusive prefix of this thread's chunk
#pragma unroll
  for (int u = 0; u < 4; ++u) {
    int b = base + u;
    if (b <= NBINS) {
      off[b] = ex;
      if (b < NBINS) cur[b] = ex;
    }
    ex += c[u];
  }
}

__global__ void k_fill(const int* __restrict__ ei, const int* __restrict__ et,
                       int* __restrict__ cur, int* __restrict__ srt,
                       float* __restrict__ deg) {
  int e = blockIdx.x * blockDim.x + threadIdx.x;
  if (e >= NE) return;
  int s = ei[e], d = ei[NE + e], r = et[e];
  int p = atomicAdd(&cur[(d >> 7) * NR + r], 1);
  srt[p] = ((d & 127) << 16) | s;        // pack (dst_low, src): src<2^15, dl<2^7
  atomicAdd(&deg[d], 1.0f);
}

// WT[k][o] = W[o][k] for the two self-loop weights (torch Linear layout -> k-major)
__global__ void k_transposeW(const float* __restrict__ W0, const float* __restrict__ W1,
                             float* __restrict__ T0, float* __restrict__ T1) {
  const float* W = blockIdx.x ? W1 : W0;
  float* T = blockIdx.x ? T1 : T0;
  for (int idx = threadIdx.x; idx < D * D; idx += 256) {
    int o = idx >> 7, k = idx & 127;
    T[k * D + o] = W[idx];
  }
}

// ---------------- fused RGCN layer ----------------
// Block nb owns dst rows [nb*128, nb*128+128). Per relation r:
//   build S[dl][k] = sum of x[src] over edges in bin (nb,r)  (LDS f32 atomics)
//   acc += S @ W_r                                            (8x8 micro GEMM)
// Then acc *= 1/deg, acc += x_rows @ Wself^T, + bias, ReLU, store.

__launch_bounds__(256, 1)
__global__ void k_fused(const float* __restrict__ x, const float* __restrict__ Wrel,
                        const float* __restrict__ WT, const float* __restrict__ Wb,
                        const int* __restrict__ srt, const int* __restrict__ off,
                        const float* __restrict__ deg, float* __restrict__ xo) {
  __shared__ float S[D][AST];    // 67,584 B
  __shared__ float Wl[D][D];     // 65,536 B  -> 133,120 total
  const int nb = blockIdx.x;
  const int row0 = nb * D;
  const int tx = threadIdx.x & 15, ty = threadIdx.x >> 4;
  const int wave = threadIdx.x >> 6, lane = threadIdx.x & 63;

  float acc[8][8];
#pragma unroll
  for (int j = 0; j < 8; ++j)
#pragma unroll
    for (int m = 0; m < 8; ++m) acc[j][m] = 0.f;

  for (int r = 0; r < NR; ++r) {
    __syncthreads();                       // prev GEMM done reading S & Wl
#pragma unroll
    for (int t = 0; t < 17; ++t) {         // zero S (128*132/4 = 4224 float4)
      int idx = threadIdx.x + 256 * t;
      if (idx < D * AST / 4)
        reinterpret_cast<float4*>(&S[0][0])[idx] = make_float4(0.f, 0.f, 0.f, 0.f);
    }
    __syncthreads();                       // S zeroed
    {                                      // stage W_r -> Wl (coalesced, overlaps gather)
      const float4* Wr4 = reinterpret_cast<const float4*>(Wrel + (size_t)r * D * D);
      float4* Wl4 = reinterpret_cast<float4*>(&Wl[0][0]);
#pragma unroll
      for (int t = 0; t < 16; ++t)
        Wl4[threadIdx.x + 256 * t] = Wr4[threadIdx.x + 256 * t];
    }
    {                                      // gather-accumulate edges, 1-deep prefetch
      const int b = nb * NR + r;
      const int end = off[b + 1];
      int i = off[b] + wave;
      int pv_n = 0;
      float2 v_n = make_float2(0.f, 0.f);
      if (i < end) {
        pv_n = srt[i];
        v_n = reinterpret_cast<const float2*>(x + (size_t)(pv_n & 0xFFFF) * D)[lane];
      }
      for (; i < end; i += 4) {
        const int pv_c = pv_n;
        const float2 v_c = v_n;
        const int i2 = i + 4;
        if (i2 < end) {
          pv_n = srt[i2];
          v_n = reinterpret_cast<const float2*>(x + (size_t)(pv_n & 0xFFFF) * D)[lane];
        }
        const int dl = pv_c >> 16;
        atomicAdd(&S[dl][2 * lane], v_c.x);       // ds_add_f32, 2-way bank = free
        atomicAdd(&S[dl][2 * lane + 1], v_c.y);
      }
    }
    __syncthreads();                       // S & Wl ready
    for (int k = 0; k < D; k += 4) {       // acc += S @ Wl
      float4 a[8];
#pragma unroll
      for (int j = 0; j < 8; ++j)
        a[j] = *reinterpret_cast<const float4*>(&S[ty + 16 * j][k]);
#pragma unroll
      for (int kk = 0; kk < 4; ++kk) {
        float4 w0 = *reinterpret_cast<const float4*>(&Wl[k + kk][4 * tx]);
        float4 w1 = *reinterpret_cast<const float4*>(&Wl[k + kk][4 * tx + 64]);
#pragma unroll
        for (int j = 0; j < 8; ++j) {
          float av = (kk == 0) ? a[j].x : (kk == 1) ? a[j].y
                   : (kk == 2) ? a[j].z : a[j].w;
          acc[j][0] += av * w0.x; acc[j][1] += av * w0.y;
          acc[j][2] += av * w0.z; acc[j][3] += av * w0.w;
          acc[j][4] += av * w1.x; acc[j][5] += av * w1.y;
          acc[j][6] += av * w1.z; acc[j][7] += av * w1.w;
        }
      }
    }
  }

  // scale message aggregate by 1/deg (before adding self term)
#pragma unroll
  for (int j = 0; j < 8; ++j) {
    int row = row0 + ty + 16 * j;
    float dv = (row < NN) ? deg[row] : 1.f;
    float inv = 1.f / fmaxf(dv, 1.f);
#pragma unroll
    for (int m = 0; m < 8; ++m) acc[j][m] *= inv;
  }

  // self phase: acc += x_rows @ WT
  __syncthreads();
  {
    const float4* WT4 = reinterpret_cast<const float4*>(WT);
    float4* Wl4 = reinterpret_cast<float4*>(&Wl[0][0]);
#pragma unroll
    for (int t = 0; t < 16; ++t)
      Wl4[threadIdx.x + 256 * t] = WT4[threadIdx.x + 256 * t];
#pragma unroll
    for (int t = 0; t < 16; ++t) {
      int idx = threadIdx.x + 256 * t;     // 4096 float4s of S payload
      int rw = idx >> 5, c = idx & 31;
      float4 v = make_float4(0.f, 0.f, 0.f, 0.f);
      if (row0 + rw < NN)
        v = reinterpret_cast<const float4*>(x)[(size_t)(row0 + rw) * 32 + c];
      *reinterpret_cast<float4*>(&S[rw][4 * c]) = v;
    }
  }
  __syncthreads();
  for (int k = 0; k < D; k += 4) {
    float4 a[8];
#pragma unroll
    for (int j = 0; j < 8; ++j)
      a[j] = *reinterpret_cast<const float4*>(&S[ty + 16 * j][k]);
#pragma unroll
    for (int kk = 0; kk < 4; ++kk) {
      float4 w0 = *reinterpret_cast<const float4*>(&Wl[k + kk][4 * tx]);
      float4 w1 = *reinterpret_cast<const float4*>(&Wl[k + kk][4 * tx + 64]);
#pragma unroll
      for (int j = 0; j < 8; ++j) {
        float av = (kk == 0) ? a[j].x : (kk == 1) ? a[j].y
                 : (kk == 2) ? a[j].z : a[j].w;
        acc[j][0] += av * w0.x; acc[j][1] += av * w0.y;
        acc[j][2] += av * w0.z; acc[j][3] += av * w0.w;
        acc[j][4] += av * w1.x; acc[j][5] += av * w1.y;
        acc[j][6] += av * w1.z; acc[j][7] += av * w1.w;
      }
    }
  }

  // epilogue: relu(acc + bias), float4 stores (cols 4tx..4tx+3 and +64)
  const float4 b0 = reinterpret_cast<const float4*>(Wb)[tx];
  const float4 b1 = reinterpret_cast<const float4*>(Wb)[tx + 16];
#pragma unroll
  for (int j = 0; j < 8; ++j) {
    int row = row0 + ty + 16 * j;
    if (row < NN) {
      float4 o0, o1;
      o0.x = fmaxf(acc[j][0] + b0.x, 0.f);
      o0.y = fmaxf(acc[j][1] + b0.y, 0.f);
      o0.z = fmaxf(acc[j][2] + b0.z, 0.f);
      o0.w = fmaxf(acc[j][3] + b0.w, 0.f);
      o1.x = fmaxf(acc[j][4] + b1.x, 0.f);
      o1.y = fmaxf(acc[j][5] + b1.y, 0.f);
      o1.z = fmaxf(acc[j][6] + b1.z, 0.f);
      o1.w = fmaxf(acc[j][7] + b1.w, 0.f);
      reinterpret_cast<float4*>(xo + (size_t)row * D)[tx] = o0;
      reinterpret_cast<float4*>(xo + (size_t)row * D)[tx + 16] = o1;
    }
  }
}

// ---------------- DistMult scoring ----------------

__global__ void k_score(const float* __restrict__ x, const float* __restrict__ rel,
                        const int* __restrict__ hh, const int* __restrict__ rr,
                        const int* __restrict__ tt, float* __restrict__ out) {
  int gw = (blockIdx.x * blockDim.x + threadIdx.x) >> 6;
  int lane = threadIdx.x & 63;
  int nw = (gridDim.x * blockDim.x) >> 6;
  for (int i = gw; i < NT; i += nw) {
    const float2* ph = reinterpret_cast<const float2*>(x + (size_t)hh[i] * D);
    const float2* pr = reinterpret_cast<const float2*>(rel + (size_t)rr[i] * D);
    const float2* pt = reinterpret_cast<const float2*>(x + (size_t)tt[i] * D);
    float2 a = ph[lane], b = pr[lane], c = pt[lane];
    float v = a.x * b.x * c.x + a.y * b.y * c.y;
#pragma unroll
    for (int m = 32; m; m >>= 1) v += __shfl_xor(v, m);
    if (lane == 0) out[i] = v;
  }
}

// ---------------- launch ----------------

extern "C" void kernel_launch(void* const* d_in, const int* in_sizes, int n_in,
                              void* d_out, int out_size, void* d_ws, size_t ws_size,
                              hipStream_t stream) {
  const float* node_emb = (const float*)d_in[0];
  const float* rel_emb  = (const float*)d_in[1];
  const float* W_rel0   = (const float*)d_in[2];
  const float* Wself_w0 = (const float*)d_in[3];
  const float* Wself_b0 = (const float*)d_in[4];
  const float* W_rel1   = (const float*)d_in[5];
  const float* Wself_w1 = (const float*)d_in[6];
  const float* Wself_b1 = (const float*)d_in[7];
  const int* local_nodes = (const int*)d_in[8];
  const int* edge_index  = (const int*)d_in[9];
  const int* edge_type   = (const int*)d_in[10];
  const int* h_loc = (const int*)d_in[11];
  const int* r_ids = (const int*)d_in[12];
  const int* t_loc = (const int*)d_in[13];
  float* out = (float*)d_out;

  // workspace layout (bytes)
  char* ws = (char*)d_ws;
  float* x_a = (float*)(ws + 0);             // 15,360,000
  float* x_b = (float*)(ws + 15360000);      // 15,360,000
  float* WT0 = (float*)(ws + 30720000);      //     65,536
  float* WT1 = (float*)(ws + 30785536);      //     65,536
  float* deg = (float*)(ws + 30851072);      //    120,000
  int* bins  = (int*)(ws + 30971072);        //     15,040
  int* off   = (int*)(ws + 30986112);        //     15,044 (3761 ints)
  int* cur   = (int*)(ws + 31001156);        //     15,040
  int* srt   = (int*)(ws + 31016196);        //  1,920,000
  if (ws_size < (size_t)32936196) return;    // total need

  // zero deg + bins (contiguous); off/cur/srt are fully overwritten downstream
  hipMemsetAsync(ws + 30851072, 0, 135040, stream);

  k_gather_x<<<3750, 256, 0, stream>>>(node_emb, local_nodes, x_a);
  k_hist_bins<<<1875, 256, 0, stream>>>(edge_index, edge_type, bins);
  k_scan_bins<<<1, 1024, 0, stream>>>(bins, off, cur);
  k_fill<<<1875, 256, 0, stream>>>(edge_index, edge_type, cur, srt, deg);
  k_transposeW<<<2, 256, 0, stream>>>(Wself_w0, Wself_w1, WT0, WT1);

  k_fused<<<NBLK, 256, 0, stream>>>(x_a, W_rel0, WT0, Wself_b0, srt, off, deg, x_b);
  k_fused<<<NBLK, 256, 0, stream>>>(x_b, W_rel1, WT1, Wself_b1, srt, off, deg, x_a);

  k_score<<<1024, 256, 0, stream>>>(x_a, rel_emb, h_loc, r_ids, t_loc, out);
}